// Round 8
// baseline (1039.144 us; speedup 1.0000x reference)
//
#include <hip/hip_runtime.h>
#include <hip/hip_bf16.h>
#include <hip/hip_fp16.h>
#include <math.h>

#define NN 100000
#define NE 3200000
#define NF 256
#define NH 128
#define NC 40
#define BN_EPS 1e-5f
#define NCOPY 8

typedef __attribute__((ext_vector_type(8))) short bf16x8;
typedef __attribute__((ext_vector_type(4))) float f32x4;

__device__ __forceinline__ float2 bf2_unpack(unsigned int v) {
    return make_float2(__uint_as_float(v << 16), __uint_as_float(v & 0xffff0000u));
}
__device__ __forceinline__ unsigned int pack2bf(float lo, float hi) {
    unsigned int a = (unsigned int)__hip_bfloat16_raw(__float2bfloat16(lo)).x;
    unsigned int b = (unsigned int)__hip_bfloat16_raw(__float2bfloat16(hi)).x;
    return a | (b << 16);
}

// ---------------- init: hist8=0, sums=0 ----------------
__global__ __launch_bounds__(256) void k_init(unsigned long long* hist8, float* sums) {
    int i = blockIdx.x * 256 + threadIdx.x;
    if (i < NCOPY * NN) hist8[i] = 0ULL;
    if (i < 3 * 1024) sums[i] = 0.0f;
}

// ---------------- edge pass: XCD-private u64 packed atomic (count | 12.32 weight sum) ----------------
// copy index = blockIdx & 7 tracks the round-robin block->XCD dispatch, keeping the
// RMW line in one XCD's L2 (no cross-die ping-pong). Return count = slot within copy.
__global__ __launch_bounds__(256) void k_edge(const int* __restrict__ ei, const float* __restrict__ ew,
                                              unsigned long long* __restrict__ hist8,
                                              int* __restrict__ pos) {
    int e = blockIdx.x * 256 + threadIdx.x;
    if (e >= NE) return;
    int c = blockIdx.x & (NCOPY - 1);
    int d = __builtin_nontemporal_load(&ei[NE + e]);
    float w = __builtin_nontemporal_load(&ew[e]);
    unsigned long long pack = (1ULL << 44) | (unsigned long long)(w * 4294967296.0f);
    unsigned long long old = atomicAdd(&hist8[(size_t)c * NN + d], pack);
    __builtin_nontemporal_store((int)(old >> 44), &pos[e]);
}

// ---------------- combine copies: dinv, counts, per-copy exclusive starts ----------------
__global__ __launch_bounds__(256) void k_combine(unsigned long long* __restrict__ hist8,
                                                 float* __restrict__ dinv,
                                                 int* __restrict__ counts) {
    int i = blockIdx.x * 256 + threadIdx.x;
    if (i >= NN) return;
    int tot = 0;
    unsigned long long wsum = 0;
    int start[NCOPY];
#pragma unroll
    for (int c = 0; c < NCOPY; c++) {
        unsigned long long h = hist8[(size_t)c * NN + i];
        start[c] = tot;
        tot += (int)(h >> 44);
        wsum += (h & 0xFFFFFFFFFFFULL);
    }
#pragma unroll
    for (int c = 0; c < NCOPY; c++) hist8[(size_t)c * NN + i] = (unsigned long long)start[c];
    counts[i] = tot;
    float ws = (float)wsum * 2.3283064365386963e-10f;
    dinv[i] = rsqrtf(1.0f + ws);
}

// ---------------- single-block exclusive scan of counts -> rowptr (4 elems/thread) ----------------
__global__ __launch_bounds__(1024) void k_scan(const int* __restrict__ counts,
                                               int* __restrict__ rowptr) {
    __shared__ int wsum[16];
    __shared__ int s_carry;
    int t = threadIdx.x;
    int lane = t & 63, wid = t >> 6;
    if (t == 0) s_carry = 0;
    __syncthreads();
    for (int base = 0; base < NN; base += 4096) {
        int i0 = base + t * 4;
        int c[4];
#pragma unroll
        for (int j = 0; j < 4; j++) {
            int i = i0 + j;
            c[j] = (i < NN) ? counts[i] : 0;
        }
        int v = c[0] + c[1] + c[2] + c[3];
        int x = v;
#pragma unroll
        for (int off = 1; off < 64; off <<= 1) {
            int y = __shfl_up(x, off);
            if (lane >= off) x += y;
        }
        if (lane == 63) wsum[wid] = x;
        __syncthreads();
        if (wid == 0 && lane < 16) {
            int s = wsum[lane];
#pragma unroll
            for (int off = 1; off < 16; off <<= 1) {
                int y = __shfl_up(s, off);
                if (lane >= off) s += y;
            }
            wsum[lane] = s;
        }
        __syncthreads();
        int woff = (wid > 0) ? wsum[wid - 1] : 0;
        int incl = x + woff;
        int carry = s_carry;
        int run = carry + incl - v;
#pragma unroll
        for (int j = 0; j < 4; j++) {
            int i = i0 + j;
            if (i < NN) rowptr[i] = run;
            run += c[j];
        }
        __syncthreads();
        if (t == 1023) s_carry = carry + incl;
        __syncthreads();
    }
    if (t == 0) rowptr[NN] = s_carry;
}

// ---------------- scatter edges into CSR (no atomics), packed u32 (src | f16norm<<17) ----------------
__global__ __launch_bounds__(256) void k_scatter(const int* __restrict__ ei, const float* __restrict__ ew,
                                                 const float* __restrict__ dinv,
                                                 const int* __restrict__ rowptr,
                                                 const unsigned long long* __restrict__ hist8,
                                                 const int* __restrict__ pos,
                                                 unsigned int* __restrict__ cw) {
    int e = blockIdx.x * 256 + threadIdx.x;
    if (e >= NE) return;
    int c = blockIdx.x & (NCOPY - 1);
    int s = __builtin_nontemporal_load(&ei[e]);
    int d = __builtin_nontemporal_load(&ei[NE + e]);
    float w = __builtin_nontemporal_load(&ew[e]);
    float nv = dinv[s] * w * dinv[d];
    unsigned int h = (unsigned int)__half_as_ushort(__float2half(nv)) & 0x7fffu;
    unsigned int packed = (unsigned int)s | (h << 17);
    int p = __builtin_nontemporal_load(&pos[e]);
    int slot = rowptr[d] + (int)hist8[(size_t)c * NN + d] + p;
    __builtin_nontemporal_store(packed, &cw[slot]);
}

// ---------------- MFMA bf16 GEMM: out_bf16[NN,128] = H[NN,K](ld=ldh,f32) @ W[K,128] ----------------
template <int K>
__global__ __launch_bounds__(256) void k_gemm_mfma(const float* __restrict__ H, int ldh,
                                                   const float* __restrict__ W,
                                                   __hip_bfloat16* __restrict__ out) {
    __shared__ unsigned int Bt[128][20];  // 10240 B
    int t = threadIdx.x;
    int wid = t >> 6, l = t & 63;
    int l15 = l & 15, lhi = l >> 4;
    int rowbase = blockIdx.x * 128 + wid * 32;

    int ar0 = rowbase + l15;      if (ar0 >= NN) ar0 = NN - 1;
    int ar1 = rowbase + 16 + l15; if (ar1 >= NN) ar1 = NN - 1;

    f32x4 acc[2][8];
#pragma unroll
    for (int rt = 0; rt < 2; rt++)
#pragma unroll
        for (int ct = 0; ct < 8; ct++) acc[rt][ct] = (f32x4){0.f, 0.f, 0.f, 0.f};

    for (int kb = 0; kb < K / 32; kb++) {
        __syncthreads();
        for (int i = t; i < 2048; i += 256) {
            int c = i & 127, k2l = i >> 7;
            int k = kb * 32 + 2 * k2l;
            Bt[c][k2l] = pack2bf(W[(size_t)k * NH + c], W[(size_t)(k + 1) * NH + c]);
        }
        __syncthreads();
        const float4* a0p = (const float4*)&H[(size_t)ar0 * ldh + kb * 32 + lhi * 8];
        const float4* a1p = (const float4*)&H[(size_t)ar1 * ldh + kb * 32 + lhi * 8];
        float4 x0 = a0p[0], x1 = a0p[1];
        float4 y0 = a1p[0], y1 = a1p[1];
        union { unsigned int u[4]; bf16x8 v; } af0, af1;
        af0.u[0] = pack2bf(x0.x, x0.y); af0.u[1] = pack2bf(x0.z, x0.w);
        af0.u[2] = pack2bf(x1.x, x1.y); af0.u[3] = pack2bf(x1.z, x1.w);
        af1.u[0] = pack2bf(y0.x, y0.y); af1.u[1] = pack2bf(y0.z, y0.w);
        af1.u[2] = pack2bf(y1.x, y1.y); af1.u[3] = pack2bf(y1.z, y1.w);
#pragma unroll
        for (int ct = 0; ct < 8; ct++) {
            bf16x8 b = *(const bf16x8*)&Bt[ct * 16 + l15][lhi * 4];
            acc[0][ct] = __builtin_amdgcn_mfma_f32_16x16x32_bf16(af0.v, b, acc[0][ct], 0, 0, 0);
            acc[1][ct] = __builtin_amdgcn_mfma_f32_16x16x32_bf16(af1.v, b, acc[1][ct], 0, 0, 0);
        }
    }
#pragma unroll
    for (int rt = 0; rt < 2; rt++)
#pragma unroll
        for (int ct = 0; ct < 8; ct++)
#pragma unroll
            for (int reg = 0; reg < 4; reg++) {
                int row = rowbase + rt * 16 + lhi * 4 + reg;
                if (row < NN)
                    out[(size_t)row * NH + ct * 16 + l15] = __float2bfloat16(acc[rt][ct][reg]);
            }
}

// ---------------- CSR gather-aggregate (bf16 lin), 16-deep gather pipeline, 4 nodes/block ----------------
__global__ __launch_bounds__(256) void k_agg(const unsigned int* __restrict__ linb,
                                             const float* __restrict__ dinv,
                                             const int* __restrict__ rowptr,
                                             const unsigned int* __restrict__ cw,
                                             const float* __restrict__ bias,
                                             float* __restrict__ outp, int do_relu) {
    int t = threadIdx.x;
    int node = blockIdx.x * 4 + (t >> 6);
    if (node >= NN) return;
    int ch = t & 63;
    int c = ch << 1;
    float di = dinv[node];
    float2 sv = bf2_unpack(linb[(size_t)node * 64 + ch]);
    float a0 = fmaf(sv.x, di * di, bias[c]);
    float a1 = fmaf(sv.y, di * di, bias[c + 1]);
    int beg = rowptr[node], end = rowptr[node + 1];
    int j = beg;
    for (; j + 16 <= end; j += 16) {
        unsigned int pk[16];
#pragma unroll
        for (int q = 0; q < 16; q++) pk[q] = cw[j + q];
        unsigned int v[16];
#pragma unroll
        for (int q = 0; q < 16; q++) v[q] = linb[(size_t)(pk[q] & 0x1FFFFu) * 64 + ch];
#pragma unroll
        for (int q = 0; q < 16; q++) {
            float w = __half2float(__ushort_as_half((unsigned short)(pk[q] >> 17)));
            float2 f = bf2_unpack(v[q]);
            a0 = fmaf(f.x, w, a0);
            a1 = fmaf(f.y, w, a1);
        }
    }
    for (; j + 4 <= end; j += 4) {
        unsigned int pk[4];
#pragma unroll
        for (int q = 0; q < 4; q++) pk[q] = cw[j + q];
        unsigned int v[4];
#pragma unroll
        for (int q = 0; q < 4; q++) v[q] = linb[(size_t)(pk[q] & 0x1FFFFu) * 64 + ch];
#pragma unroll
        for (int q = 0; q < 4; q++) {
            float w = __half2float(__ushort_as_half((unsigned short)(pk[q] >> 17)));
            float2 f = bf2_unpack(v[q]);
            a0 = fmaf(f.x, w, a0);
            a1 = fmaf(f.y, w, a1);
        }
    }
    for (; j < end; j++) {
        unsigned int pk = cw[j];
        unsigned int vv = linb[(size_t)(pk & 0x1FFFFu) * 64 + ch];
        float w = __half2float(__ushort_as_half((unsigned short)(pk >> 17)));
        float2 f = bf2_unpack(vv);
        a0 = fmaf(f.x, w, a0);
        a1 = fmaf(f.y, w, a1);
    }
    if (do_relu) { a0 = fmaxf(a0, 0.f); a1 = fmaxf(a1, 0.f); }
    *(float2*)&outp[(size_t)node * 384 + c] = make_float2(a0, a1);
}

// ---------------- BN stats ----------------
__global__ __launch_bounds__(256) void k_stats(const float* __restrict__ pre, float* __restrict__ sums) {
    int t = threadIdx.x;
    int c = t & 127, h = t >> 7;
    float s = 0.f, s2 = 0.f;
    for (int r = blockIdx.x * 2 + h; r < NN; r += gridDim.x * 2) {
        float v = pre[(size_t)r * 384 + c];
        s += v;
        s2 = fmaf(v, v, s2);
    }
    __shared__ float ls[256], ls2[256];
    ls[t] = s; ls2[t] = s2;
    __syncthreads();
    if (t < 128) {
        atomicAdd(&sums[c], ls[t] + ls[t + 128]);
        atomicAdd(&sums[NH + c], ls2[t] + ls2[t + 128]);
    }
}

// ---------------- finalize BN ----------------
__global__ void k_bnfinal(float* __restrict__ sums, const float* __restrict__ g,
                          const float* __restrict__ beta) {
    int c = threadIdx.x;
    if (c < NH) {
        float m = sums[c] * (1.0f / NN);
        float v = sums[NH + c] * (1.0f / NN) - m * m;
        float rstd = rsqrtf(v + BN_EPS);
        float sc = g[c] * rstd;
        sums[256 + c] = sc;
        sums[384 + c] = beta[c] - m * sc;
    }
}

// ---------------- apply BN affine in place (float4) ----------------
__global__ __launch_bounds__(256) void k_bnapply(float* __restrict__ pre, const float* __restrict__ sums) {
    int idx = blockIdx.x * 256 + threadIdx.x;  // NN*32 float4's
    if (idx >= NN * 32) return;
    int n = idx >> 5, cp = (idx & 31) << 2;
    float4 sc = *(const float4*)&sums[256 + cp];
    float4 sh = *(const float4*)&sums[384 + cp];
    float4 v = *(float4*)&pre[(size_t)n * 384 + cp];
    v.x = fmaf(v.x, sc.x, sh.x);
    v.y = fmaf(v.y, sc.y, sh.y);
    v.z = fmaf(v.z, sc.z, sh.z);
    v.w = fmaf(v.w, sc.w, sh.w);
    *(float4*)&pre[(size_t)n * 384 + cp] = v;
}

// ---------------- final linear [NN,384]@[384,40] via MFMA + softmax ----------------
__global__ __launch_bounds__(256) void k_final(const float* __restrict__ embed,
                                               const float* __restrict__ linW,
                                               const float* __restrict__ linb,
                                               float* __restrict__ logits, float* __restrict__ probs) {
    __shared__ unsigned int Wt[3 * 16 * 196];  // 37632 B
    int t = threadIdx.x;
    for (int i = t; i < 3 * 16 * 192; i += 256) {
        int ct = i / (16 * 192);
        int rem = i - ct * (16 * 192);
        int c = rem / 192, k2 = rem - c * 192;
        int col = ct * 16 + c;
        float lo = (col < NC) ? linW[(size_t)(2 * k2) * NC + col] : 0.f;
        float hi = (col < NC) ? linW[(size_t)(2 * k2 + 1) * NC + col] : 0.f;
        Wt[(ct * 16 + c) * 196 + k2] = pack2bf(lo, hi);
    }
    __syncthreads();

    int wid = t >> 6, l = t & 63;
    int rowbase = blockIdx.x * 64 + wid * 16;
    int l15 = l & 15, lhi = l >> 4;

    int arow = rowbase + l15;
    if (arow > NN - 1) arow = NN - 1;
    const float4* ap = (const float4*)&embed[(size_t)arow * 384 + lhi * 8];

    f32x4 acc0 = {0.f, 0.f, 0.f, 0.f};
    f32x4 acc1 = {0.f, 0.f, 0.f, 0.f};
    f32x4 acc2 = {0.f, 0.f, 0.f, 0.f};

    for (int kb = 0; kb < 12; kb++) {
        float4 a0 = ap[kb * 8];
        float4 a1 = ap[kb * 8 + 1];
        union { unsigned int u[4]; bf16x8 v; } af;
        af.u[0] = pack2bf(a0.x, a0.y);
        af.u[1] = pack2bf(a0.z, a0.w);
        af.u[2] = pack2bf(a1.x, a1.y);
        af.u[3] = pack2bf(a1.z, a1.w);
        int wbase = kb * 16 + lhi * 4;
        bf16x8 b0 = *(const bf16x8*)&Wt[(0 * 16 + l15) * 196 + wbase];
        bf16x8 b1 = *(const bf16x8*)&Wt[(1 * 16 + l15) * 196 + wbase];
        bf16x8 b2 = *(const bf16x8*)&Wt[(2 * 16 + l15) * 196 + wbase];
        acc0 = __builtin_amdgcn_mfma_f32_16x16x32_bf16(af.v, b0, acc0, 0, 0, 0);
        acc1 = __builtin_amdgcn_mfma_f32_16x16x32_bf16(af.v, b1, acc1, 0, 0, 0);
        acc2 = __builtin_amdgcn_mfma_f32_16x16x32_bf16(af.v, b2, acc2, 0, 0, 0);
    }

    int col0 = 0 * 16 + l15, col1 = 1 * 16 + l15, col2 = 2 * 16 + l15;
    float lb0 = (col0 < NC) ? linb[col0] : 0.f;
    float lb1 = (col1 < NC) ? linb[col1] : 0.f;
    float lb2 = (col2 < NC) ? linb[col2] : 0.f;

#pragma unroll
    for (int reg = 0; reg < 4; reg++) {
        int row = rowbase + lhi * 4 + reg;
        float v0 = acc0[reg] + lb0;
        float v1 = acc1[reg] + lb1;
        float v2 = acc2[reg] + lb2;
        float m = fmaxf(v0, v1);
        if (col2 < NC) m = fmaxf(m, v2);
#pragma unroll
        for (int off = 1; off < 16; off <<= 1) m = fmaxf(m, __shfl_xor(m, off));
        float e0 = __expf(v0 - m);
        float e1 = __expf(v1 - m);
        float e2 = (col2 < NC) ? __expf(v2 - m) : 0.f;
        float s = e0 + e1 + e2;
#pragma unroll
        for (int off = 1; off < 16; off <<= 1) s += __shfl_xor(s, off);
        float inv = 1.0f / s;
        if (row < NN) {
            size_t base = (size_t)row * NC;
            logits[base + col0] = v0;
            probs[base + col0] = e0 * inv;
            logits[base + col1] = v1;
            probs[base + col1] = e1 * inv;
            if (col2 < NC) {
                logits[base + col2] = v2;
                probs[base + col2] = e2 * inv;
            }
        }
    }
}

extern "C" void kernel_launch(void* const* d_in, const int* in_sizes, int n_in,
                              void* d_out, int out_size, void* d_ws, size_t ws_size,
                              hipStream_t stream) {
    const float* x    = (const float*)d_in[0];
    const int*   ei   = (const int*)d_in[1];
    const float* ew   = (const float*)d_in[2];
    const float* W1   = (const float*)d_in[3];
    const float* b1   = (const float*)d_in[4];
    const float* g1   = (const float*)d_in[5];
    const float* be1  = (const float*)d_in[6];
    const float* W2   = (const float*)d_in[7];
    const float* b2   = (const float*)d_in[8];
    const float* g2   = (const float*)d_in[9];
    const float* be2  = (const float*)d_in[10];
    const float* W3   = (const float*)d_in[11];
    const float* b3   = (const float*)d_in[12];
    const float* g3   = (const float*)d_in[13];
    const float* be3  = (const float*)d_in[14];
    const float* linW = (const float*)d_in[15];
    const float* linb = (const float*)d_in[16];

    float* out    = (float*)d_out;
    float* logits = out;
    float* probs  = out + (size_t)NN * NC;
    float* embed  = out + (size_t)2 * NN * NC;

    char* ws = (char*)d_ws;
    size_t off = 0;
    auto alloc = [&](size_t bytes) -> char* {
        char* p = ws + off;
        off = (off + bytes + 255) & ~(size_t)255;
        return p;
    };
    float*              dinv   = (float*)alloc((size_t)NN * 4);
    unsigned long long* hist8  = (unsigned long long*)alloc((size_t)NCOPY * NN * 8);
    int*                counts = (int*)alloc((size_t)NN * 4);
    int*                rowptr = (int*)alloc((size_t)(NN + 1) * 4);
    unsigned int*       cw     = (unsigned int*)alloc((size_t)NE * 4);
    __hip_bfloat16*     lin    = (__hip_bfloat16*)alloc((size_t)NN * NH * 2);
    float*              sums   = (float*)alloc(3 * 1024 * 4);
    int*                pos    = (int*)lin;  // alias: pos dead before lin first written
    (void)ws_size; (void)in_sizes; (void)n_in; (void)out_size;

    int gN = (NN + 255) / 256;
    int g8 = (NCOPY * NN + 255) / 256;
    int gE = (NE + 255) / 256;
    int gM = (NN + 127) / 128;
    int gA = (NN + 3) / 4;
    int gB = (NN * 32 + 255) / 256;
    int gF = (NN + 63) / 64;

    k_init<<<g8, 256, 0, stream>>>(hist8, sums);
    k_edge<<<gE, 256, 0, stream>>>(ei, ew, hist8, pos);
    k_combine<<<gN, 256, 0, stream>>>(hist8, dinv, counts);
    k_scan<<<1, 1024, 0, stream>>>(counts, rowptr);
    k_scatter<<<gE, 256, 0, stream>>>(ei, ew, dinv, rowptr, hist8, pos, cw);

    // layer 1
    k_gemm_mfma<NF><<<gM, 256, 0, stream>>>(x, NF, W1, lin);
    k_agg<<<gA, 256, 0, stream>>>((const unsigned int*)lin, dinv, rowptr, cw, b1, embed + 0, 1);
    k_stats<<<1024, 256, 0, stream>>>(embed + 0, sums + 0);
    k_bnfinal<<<1, 128, 0, stream>>>(sums + 0, g1, be1);
    k_bnapply<<<gB, 256, 0, stream>>>(embed + 0, sums + 0);
    // layer 2
    k_gemm_mfma<NH><<<gM, 256, 0, stream>>>(embed + 0, 384, W2, lin);
    k_agg<<<gA, 256, 0, stream>>>((const unsigned int*)lin, dinv, rowptr, cw, b2, embed + 128, 1);
    k_stats<<<1024, 256, 0, stream>>>(embed + 128, sums + 1024);
    k_bnfinal<<<1, 128, 0, stream>>>(sums + 1024, g2, be2);
    k_bnapply<<<gB, 256, 0, stream>>>(embed + 128, sums + 1024);
    // layer 3 (no relu)
    k_gemm_mfma<NH><<<gM, 256, 0, stream>>>(embed + 128, 384, W3, lin);
    k_agg<<<gA, 256, 0, stream>>>((const unsigned int*)lin, dinv, rowptr, cw, b3, embed + 256, 0);
    k_stats<<<1024, 256, 0, stream>>>(embed + 256, sums + 2048);
    k_bnfinal<<<1, 128, 0, stream>>>(sums + 2048, g3, be3);
    k_bnapply<<<gB, 256, 0, stream>>>(embed + 256, sums + 2048);
    // final linear + softmax (MFMA)
    k_final<<<gF, 256, 0, stream>>>(embed, linW, linb, logits, probs);
}

// Round 9
// 989.597 us; speedup vs baseline: 1.0501x; 1.0501x over previous
//
#include <hip/hip_runtime.h>
#include <hip/hip_bf16.h>
#include <hip/hip_fp16.h>
#include <math.h>

#define NN 100000
#define NE 3200000
#define NF 256
#define NH 128
#define NC 40
#define BN_EPS 1e-5f

typedef __attribute__((ext_vector_type(8))) short bf16x8;
typedef __attribute__((ext_vector_type(4))) float f32x4;

__device__ __forceinline__ float2 bf2_unpack(unsigned int v) {
    return make_float2(__uint_as_float(v << 16), __uint_as_float(v & 0xffff0000u));
}
__device__ __forceinline__ unsigned int pack2bf(float lo, float hi) {
    unsigned int a = (unsigned int)__hip_bfloat16_raw(__float2bfloat16(lo)).x;
    unsigned int b = (unsigned int)__hip_bfloat16_raw(__float2bfloat16(hi)).x;
    return a | (b << 16);
}
__device__ __forceinline__ float4 affine4(float4 v, float4 sc, float4 sh) {
    v.x = fmaf(v.x, sc.x, sh.x);
    v.y = fmaf(v.y, sc.y, sh.y);
    v.z = fmaf(v.z, sc.z, sh.z);
    v.w = fmaf(v.w, sc.w, sh.w);
    return v;
}

// ---------------- init: hist=0, sums=0 ----------------
__global__ __launch_bounds__(256) void k_init(unsigned long long* hist, float* sums) {
    int i = blockIdx.x * 256 + threadIdx.x;
    if (i < NN) hist[i] = 0ULL;
    if (i < 3 * 1024) sums[i] = 0.0f;
}

// ---------------- shared GEMM body: out_bf16[NN,128] = H[NN,K] @ W[K,128] ----------------
// BN: apply per-k affine (scsh[k]=scale, scsh[128+k]=shift) to A in f32 before packing,
// and write the normalized A values back to Hw (replaces the separate bnapply pass).
template <int K, bool BN>
__device__ __forceinline__ void gemm_body(unsigned int (*Bt)[20], const float* H, float* Hw,
                                          const float* scsh, int ldh, const float* W,
                                          __hip_bfloat16* out, int blk, int t) {
    int wid = t >> 6, l = t & 63;
    int l15 = l & 15, lhi = l >> 4;
    int rowbase = blk * 128 + wid * 32;
    int ar0 = rowbase + l15;      if (ar0 >= NN) ar0 = NN - 1;
    int ar1 = rowbase + 16 + l15; if (ar1 >= NN) ar1 = NN - 1;

    f32x4 acc[2][8];
#pragma unroll
    for (int rt = 0; rt < 2; rt++)
#pragma unroll
        for (int ct = 0; ct < 8; ct++) acc[rt][ct] = (f32x4){0.f, 0.f, 0.f, 0.f};

    for (int kb = 0; kb < K / 32; kb++) {
        __syncthreads();
        for (int i = t; i < 2048; i += 256) {
            int c = i & 127, k2l = i >> 7;
            int k = kb * 32 + 2 * k2l;
            Bt[c][k2l] = pack2bf(W[(size_t)k * NH + c], W[(size_t)(k + 1) * NH + c]);
        }
        __syncthreads();
        int kk = kb * 32 + lhi * 8;
        const float4* a0p = (const float4*)&H[(size_t)ar0 * ldh + kk];
        const float4* a1p = (const float4*)&H[(size_t)ar1 * ldh + kk];
        float4 x0 = a0p[0], x1 = a0p[1];
        float4 y0 = a1p[0], y1 = a1p[1];
        if constexpr (BN) {
            float4 sc0 = *(const float4*)&scsh[kk];
            float4 sc1 = *(const float4*)&scsh[kk + 4];
            float4 sh0 = *(const float4*)&scsh[128 + kk];
            float4 sh1 = *(const float4*)&scsh[128 + kk + 4];
            x0 = affine4(x0, sc0, sh0); x1 = affine4(x1, sc1, sh1);
            y0 = affine4(y0, sc0, sh0); y1 = affine4(y1, sc1, sh1);
            *(float4*)&Hw[(size_t)ar0 * ldh + kk] = x0;
            *(float4*)&Hw[(size_t)ar0 * ldh + kk + 4] = x1;
            *(float4*)&Hw[(size_t)ar1 * ldh + kk] = y0;
            *(float4*)&Hw[(size_t)ar1 * ldh + kk + 4] = y1;
        }
        union { unsigned int u[4]; bf16x8 v; } af0, af1;
        af0.u[0] = pack2bf(x0.x, x0.y); af0.u[1] = pack2bf(x0.z, x0.w);
        af0.u[2] = pack2bf(x1.x, x1.y); af0.u[3] = pack2bf(x1.z, x1.w);
        af1.u[0] = pack2bf(y0.x, y0.y); af1.u[1] = pack2bf(y0.z, y0.w);
        af1.u[2] = pack2bf(y1.x, y1.y); af1.u[3] = pack2bf(y1.z, y1.w);
#pragma unroll
        for (int ct = 0; ct < 8; ct++) {
            bf16x8 b = *(const bf16x8*)&Bt[ct * 16 + l15][lhi * 4];
            acc[0][ct] = __builtin_amdgcn_mfma_f32_16x16x32_bf16(af0.v, b, acc[0][ct], 0, 0, 0);
            acc[1][ct] = __builtin_amdgcn_mfma_f32_16x16x32_bf16(af1.v, b, acc[1][ct], 0, 0, 0);
        }
    }
#pragma unroll
    for (int rt = 0; rt < 2; rt++)
#pragma unroll
        for (int ct = 0; ct < 8; ct++)
#pragma unroll
            for (int reg = 0; reg < 4; reg++) {
                int row = rowbase + rt * 16 + lhi * 4 + reg;
                if (row < NN)
                    out[(size_t)row * NH + ct * 16 + l15] = __float2bfloat16(acc[rt][ct][reg]);
            }
}

// ---------------- fat kernel: GEMM layer-1 (blocks < gm) + edge histogram (blocks >= gm) ----------------
// Independent work items fused so gemm1's time hides under the atomic-service-bound edge pass.
__global__ __launch_bounds__(256) void k_g1edge(const float* __restrict__ x, const float* __restrict__ W1,
                                                __hip_bfloat16* __restrict__ lin,
                                                const int* __restrict__ ei, const float* __restrict__ ew,
                                                unsigned long long* __restrict__ hist,
                                                int* __restrict__ pos, int gm) {
    __shared__ unsigned int Bt[128][20];
    int t = threadIdx.x;
    int blk = (int)blockIdx.x;
    if (blk < gm) {
        gemm_body<NF, false>(Bt, x, nullptr, nullptr, NF, W1, lin, blk, t);
    } else {
        int e = (blk - gm) * 256 + t;
        if (e < NE) {
            int d = __builtin_nontemporal_load(&ei[NE + e]);
            float w = __builtin_nontemporal_load(&ew[e]);
            unsigned long long pk = (1ULL << 44) | (unsigned long long)(w * 4294967296.0f);
            unsigned long long old = atomicAdd(&hist[d], pk);
            __builtin_nontemporal_store((int)(old >> 44), &pos[e]);
        }
    }
}

// ---------------- BN-fused GEMM for layers 2/3 ----------------
__global__ __launch_bounds__(256) void k_gemm_bn(const float* H, float* Hw,
                                                 const float* __restrict__ scsh,
                                                 const float* __restrict__ W,
                                                 __hip_bfloat16* __restrict__ out) {
    __shared__ unsigned int Bt[128][20];
    gemm_body<NH, true>(Bt, H, Hw, scsh, 384, W, out, (int)blockIdx.x, (int)threadIdx.x);
}

// ---------------- dinv = rsqrt(1 + fixedsum * 2^-32) ----------------
__global__ __launch_bounds__(256) void k_dinv(const unsigned long long* __restrict__ hist,
                                              float* __restrict__ dinv) {
    int i = blockIdx.x * 256 + threadIdx.x;
    if (i < NN) {
        float ws = (float)(hist[i] & 0xFFFFFFFFFFFULL) * 2.3283064365386963e-10f;
        dinv[i] = rsqrtf(1.0f + ws);
    }
}

// ---------------- single-block exclusive scan of hist counts -> rowptr ----------------
__global__ __launch_bounds__(1024) void k_scan(const unsigned long long* __restrict__ hist,
                                               int* __restrict__ rowptr) {
    __shared__ int wsum[16];
    __shared__ int s_carry;
    int t = threadIdx.x;
    int lane = t & 63, wid = t >> 6;
    if (t == 0) s_carry = 0;
    __syncthreads();
    for (int base = 0; base < NN; base += 4096) {
        int i0 = base + t * 4;
        int c[4];
#pragma unroll
        for (int j = 0; j < 4; j++) {
            int i = i0 + j;
            c[j] = (i < NN) ? (int)(hist[i] >> 44) : 0;
        }
        int v = c[0] + c[1] + c[2] + c[3];
        int x = v;
#pragma unroll
        for (int off = 1; off < 64; off <<= 1) {
            int y = __shfl_up(x, off);
            if (lane >= off) x += y;
        }
        if (lane == 63) wsum[wid] = x;
        __syncthreads();
        if (wid == 0 && lane < 16) {
            int s = wsum[lane];
#pragma unroll
            for (int off = 1; off < 16; off <<= 1) {
                int y = __shfl_up(s, off);
                if (lane >= off) s += y;
            }
            wsum[lane] = s;
        }
        __syncthreads();
        int woff = (wid > 0) ? wsum[wid - 1] : 0;
        int incl = x + woff;
        int carry = s_carry;
        int run = carry + incl - v;
#pragma unroll
        for (int j = 0; j < 4; j++) {
            int i = i0 + j;
            if (i < NN) rowptr[i] = run;
            run += c[j];
        }
        __syncthreads();
        if (t == 1023) s_carry = carry + incl;
        __syncthreads();
    }
    if (t == 0) rowptr[NN] = s_carry;
}

// ---------------- scatter edges into CSR (no atomics), packed u32 (src | f16norm<<17) ----------------
__global__ __launch_bounds__(256) void k_scatter(const int* __restrict__ ei, const float* __restrict__ ew,
                                                 const float* __restrict__ dinv,
                                                 const int* __restrict__ rowptr,
                                                 const int* __restrict__ pos,
                                                 unsigned int* __restrict__ cw) {
    int e = blockIdx.x * 256 + threadIdx.x;
    if (e >= NE) return;
    int s = __builtin_nontemporal_load(&ei[e]);
    int d = __builtin_nontemporal_load(&ei[NE + e]);
    float w = __builtin_nontemporal_load(&ew[e]);
    float nv = dinv[s] * w * dinv[d];
    unsigned int h = (unsigned int)__half_as_ushort(__float2half(nv)) & 0x7fffu;
    unsigned int packed = (unsigned int)s | (h << 17);
    int p = __builtin_nontemporal_load(&pos[e]);
    __builtin_nontemporal_store(packed, &cw[rowptr[d] + p]);
}

// ---------------- CSR gather-aggregate (bf16 lin), 16-deep gather pipeline, 4 nodes/block ----------------
__global__ __launch_bounds__(256) void k_agg(const unsigned int* __restrict__ linb,
                                             const float* __restrict__ dinv,
                                             const int* __restrict__ rowptr,
                                             const unsigned int* __restrict__ cw,
                                             const float* __restrict__ bias,
                                             float* __restrict__ outp, int do_relu) {
    int t = threadIdx.x;
    int node = blockIdx.x * 4 + (t >> 6);
    if (node >= NN) return;
    int ch = t & 63;
    int c = ch << 1;
    float di = dinv[node];
    float2 sv = bf2_unpack(linb[(size_t)node * 64 + ch]);
    float a0 = fmaf(sv.x, di * di, bias[c]);
    float a1 = fmaf(sv.y, di * di, bias[c + 1]);
    int beg = rowptr[node], end = rowptr[node + 1];
    int j = beg;
    for (; j + 16 <= end; j += 16) {
        unsigned int pk[16];
#pragma unroll
        for (int q = 0; q < 16; q++) pk[q] = cw[j + q];
        unsigned int v[16];
#pragma unroll
        for (int q = 0; q < 16; q++) v[q] = linb[(size_t)(pk[q] & 0x1FFFFu) * 64 + ch];
#pragma unroll
        for (int q = 0; q < 16; q++) {
            float w = __half2float(__ushort_as_half((unsigned short)(pk[q] >> 17)));
            float2 f = bf2_unpack(v[q]);
            a0 = fmaf(f.x, w, a0);
            a1 = fmaf(f.y, w, a1);
        }
    }
    for (; j + 4 <= end; j += 4) {
        unsigned int pk[4];
#pragma unroll
        for (int q = 0; q < 4; q++) pk[q] = cw[j + q];
        unsigned int v[4];
#pragma unroll
        for (int q = 0; q < 4; q++) v[q] = linb[(size_t)(pk[q] & 0x1FFFFu) * 64 + ch];
#pragma unroll
        for (int q = 0; q < 4; q++) {
            float w = __half2float(__ushort_as_half((unsigned short)(pk[q] >> 17)));
            float2 f = bf2_unpack(v[q]);
            a0 = fmaf(f.x, w, a0);
            a1 = fmaf(f.y, w, a1);
        }
    }
    for (; j < end; j++) {
        unsigned int pk = cw[j];
        unsigned int vv = linb[(size_t)(pk & 0x1FFFFu) * 64 + ch];
        float w = __half2float(__ushort_as_half((unsigned short)(pk >> 17)));
        float2 f = bf2_unpack(vv);
        a0 = fmaf(f.x, w, a0);
        a1 = fmaf(f.y, w, a1);
    }
    if (do_relu) { a0 = fmaxf(a0, 0.f); a1 = fmaxf(a1, 0.f); }
    *(float2*)&outp[(size_t)node * 384 + c] = make_float2(a0, a1);
}

// ---------------- BN stats ----------------
__global__ __launch_bounds__(256) void k_stats(const float* __restrict__ pre, float* __restrict__ sums) {
    int t = threadIdx.x;
    int c = t & 127, h = t >> 7;
    float s = 0.f, s2 = 0.f;
    for (int r = blockIdx.x * 2 + h; r < NN; r += gridDim.x * 2) {
        float v = pre[(size_t)r * 384 + c];
        s += v;
        s2 = fmaf(v, v, s2);
    }
    __shared__ float ls[256], ls2[256];
    ls[t] = s; ls2[t] = s2;
    __syncthreads();
    if (t < 128) {
        atomicAdd(&sums[c], ls[t] + ls[t + 128]);
        atomicAdd(&sums[NH + c], ls2[t] + ls2[t + 128]);
    }
}

// ---------------- finalize BN: scale/shift per channel ----------------
__global__ void k_bnfinal(float* __restrict__ sums, const float* __restrict__ g,
                          const float* __restrict__ beta) {
    int c = threadIdx.x;
    if (c < NH) {
        float m = sums[c] * (1.0f / NN);
        float v = sums[NH + c] * (1.0f / NN) - m * m;
        float rstd = rsqrtf(v + BN_EPS);
        float sc = g[c] * rstd;
        sums[256 + c] = sc;
        sums[384 + c] = beta[c] - m * sc;
    }
}

// ---------------- final linear [NN,384]@[384,40] via MFMA + softmax; BN3 fused on x3 cols ----------------
__global__ __launch_bounds__(256) void k_final(const float* __restrict__ embed, float* embedW,
                                               const float* __restrict__ scsh3,
                                               const float* __restrict__ linW,
                                               const float* __restrict__ linb,
                                               float* __restrict__ logits, float* __restrict__ probs) {
    __shared__ unsigned int Wt[3 * 16 * 196];  // 37632 B
    int t = threadIdx.x;
    for (int i = t; i < 3 * 16 * 192; i += 256) {
        int ct = i / (16 * 192);
        int rem = i - ct * (16 * 192);
        int c = rem / 192, k2 = rem - c * 192;
        int col = ct * 16 + c;
        float lo = (col < NC) ? linW[(size_t)(2 * k2) * NC + col] : 0.f;
        float hi = (col < NC) ? linW[(size_t)(2 * k2 + 1) * NC + col] : 0.f;
        Wt[(ct * 16 + c) * 196 + k2] = pack2bf(lo, hi);
    }
    __syncthreads();

    int wid = t >> 6, l = t & 63;
    int rowbase = blockIdx.x * 64 + wid * 16;
    int l15 = l & 15, lhi = l >> 4;

    int arow = rowbase + l15;
    if (arow > NN - 1) arow = NN - 1;
    const float4* ap = (const float4*)&embed[(size_t)arow * 384 + lhi * 8];

    f32x4 acc0 = {0.f, 0.f, 0.f, 0.f};
    f32x4 acc1 = {0.f, 0.f, 0.f, 0.f};
    f32x4 acc2 = {0.f, 0.f, 0.f, 0.f};

    for (int kb = 0; kb < 12; kb++) {
        float4 a0 = ap[kb * 8];
        float4 a1 = ap[kb * 8 + 1];
        if (kb >= 8) {  // x3 columns: apply BN3 affine, write normalized back (replaces bnapply)
            int kk = kb * 32 + lhi * 8 - 256;
            float4 sc0 = *(const float4*)&scsh3[kk];
            float4 sc1 = *(const float4*)&scsh3[kk + 4];
            float4 sh0 = *(const float4*)&scsh3[128 + kk];
            float4 sh1 = *(const float4*)&scsh3[128 + kk + 4];
            a0 = affine4(a0, sc0, sh0);
            a1 = affine4(a1, sc1, sh1);
            *(float4*)&embedW[(size_t)arow * 384 + kb * 32 + lhi * 8] = a0;
            *(float4*)&embedW[(size_t)arow * 384 + kb * 32 + lhi * 8 + 4] = a1;
        }
        union { unsigned int u[4]; bf16x8 v; } af;
        af.u[0] = pack2bf(a0.x, a0.y);
        af.u[1] = pack2bf(a0.z, a0.w);
        af.u[2] = pack2bf(a1.x, a1.y);
        af.u[3] = pack2bf(a1.z, a1.w);
        int wbase = kb * 16 + lhi * 4;
        bf16x8 b0 = *(const bf16x8*)&Wt[(0 * 16 + l15) * 196 + wbase];
        bf16x8 b1 = *(const bf16x8*)&Wt[(1 * 16 + l15) * 196 + wbase];
        bf16x8 b2 = *(const bf16x8*)&Wt[(2 * 16 + l15) * 196 + wbase];
        acc0 = __builtin_amdgcn_mfma_f32_16x16x32_bf16(af.v, b0, acc0, 0, 0, 0);
        acc1 = __builtin_amdgcn_mfma_f32_16x16x32_bf16(af.v, b1, acc1, 0, 0, 0);
        acc2 = __builtin_amdgcn_mfma_f32_16x16x32_bf16(af.v, b2, acc2, 0, 0, 0);
    }

    int col0 = 0 * 16 + l15, col1 = 1 * 16 + l15, col2 = 2 * 16 + l15;
    float lb0 = (col0 < NC) ? linb[col0] : 0.f;
    float lb1 = (col1 < NC) ? linb[col1] : 0.f;
    float lb2 = (col2 < NC) ? linb[col2] : 0.f;

#pragma unroll
    for (int reg = 0; reg < 4; reg++) {
        int row = rowbase + lhi * 4 + reg;
        float v0 = acc0[reg] + lb0;
        float v1 = acc1[reg] + lb1;
        float v2 = acc2[reg] + lb2;
        float m = fmaxf(v0, v1);
        if (col2 < NC) m = fmaxf(m, v2);
#pragma unroll
        for (int off = 1; off < 16; off <<= 1) m = fmaxf(m, __shfl_xor(m, off));
        float e0 = __expf(v0 - m);
        float e1 = __expf(v1 - m);
        float e2 = (col2 < NC) ? __expf(v2 - m) : 0.f;
        float s = e0 + e1 + e2;
#pragma unroll
        for (int off = 1; off < 16; off <<= 1) s += __shfl_xor(s, off);
        float inv = 1.0f / s;
        if (row < NN) {
            size_t base = (size_t)row * NC;
            logits[base + col0] = v0;
            probs[base + col0] = e0 * inv;
            logits[base + col1] = v1;
            probs[base + col1] = e1 * inv;
            if (col2 < NC) {
                logits[base + col2] = v2;
                probs[base + col2] = e2 * inv;
            }
        }
    }
}

extern "C" void kernel_launch(void* const* d_in, const int* in_sizes, int n_in,
                              void* d_out, int out_size, void* d_ws, size_t ws_size,
                              hipStream_t stream) {
    const float* x    = (const float*)d_in[0];
    const int*   ei   = (const int*)d_in[1];
    const float* ew   = (const float*)d_in[2];
    const float* W1   = (const float*)d_in[3];
    const float* b1   = (const float*)d_in[4];
    const float* g1   = (const float*)d_in[5];
    const float* be1  = (const float*)d_in[6];
    const float* W2   = (const float*)d_in[7];
    const float* b2   = (const float*)d_in[8];
    const float* g2   = (const float*)d_in[9];
    const float* be2  = (const float*)d_in[10];
    const float* W3   = (const float*)d_in[11];
    const float* b3   = (const float*)d_in[12];
    const float* g3   = (const float*)d_in[13];
    const float* be3  = (const float*)d_in[14];
    const float* linW = (const float*)d_in[15];
    const float* linb = (const float*)d_in[16];

    float* out    = (float*)d_out;
    float* logits = out;
    float* probs  = out + (size_t)NN * NC;
    float* embed  = out + (size_t)2 * NN * NC;

    char* ws = (char*)d_ws;
    size_t off = 0;
    auto alloc = [&](size_t bytes) -> char* {
        char* p = ws + off;
        off = (off + bytes + 255) & ~(size_t)255;
        return p;
    };
    float*              dinv   = (float*)alloc((size_t)NN * 4);
    unsigned long long* hist   = (unsigned long long*)alloc((size_t)NN * 8);
    int*                rowptr = (int*)alloc((size_t)(NN + 1) * 4);
    unsigned int*       cw     = (unsigned int*)alloc((size_t)NE * 4);
    __hip_bfloat16*     lin    = (__hip_bfloat16*)alloc((size_t)NN * NH * 2);
    int*                pos    = (int*)alloc((size_t)NE * 4);  // no longer aliases lin (concurrent in fat kernel)
    float*              sums   = (float*)alloc(3 * 1024 * 4);
    (void)ws_size; (void)in_sizes; (void)n_in; (void)out_size;

    int gN = (NN + 255) / 256;
    int gE = (NE + 255) / 256;
    int gM = (NN + 127) / 128;
    int gA = (NN + 3) / 4;
    int gF = (NN + 63) / 64;

    k_init<<<gN, 256, 0, stream>>>(hist, sums);
    // fused: GEMM layer-1 (gM blocks) + edge histogram pass (gE blocks)
    k_g1edge<<<gM + gE, 256, 0, stream>>>(x, W1, lin, ei, ew, hist, pos, gM);
    k_dinv<<<gN, 256, 0, stream>>>(hist, dinv);
    k_scan<<<1, 1024, 0, stream>>>(hist, rowptr);
    k_scatter<<<gE, 256, 0, stream>>>(ei, ew, dinv, rowptr, pos, cw);

    // layer 1 aggregation + stats
    k_agg<<<gA, 256, 0, stream>>>((const unsigned int*)lin, dinv, rowptr, cw, b1, embed + 0, 1);
    k_stats<<<1024, 256, 0, stream>>>(embed + 0, sums + 0);
    k_bnfinal<<<1, 128, 0, stream>>>(sums + 0, g1, be1);
    // layer 2: GEMM reads raw x1, applies BN1 affine, writes normalized x1 back + lin2
    k_gemm_bn<<<gM, 256, 0, stream>>>(embed + 0, embed + 0, sums + 256, W2, lin);
    k_agg<<<gA, 256, 0, stream>>>((const unsigned int*)lin, dinv, rowptr, cw, b2, embed + 128, 1);
    k_stats<<<1024, 256, 0, stream>>>(embed + 128, sums + 1024);
    k_bnfinal<<<1, 128, 0, stream>>>(sums + 1024, g2, be2);
    // layer 3: GEMM reads raw x2, applies BN2 affine, writes normalized x2 back + lin3
    k_gemm_bn<<<gM, 256, 0, stream>>>(embed + 128, embed + 128, sums + 1024 + 256, W3, lin);
    k_agg<<<gA, 256, 0, stream>>>((const unsigned int*)lin, dinv, rowptr, cw, b3, embed + 256, 0);
    k_stats<<<1024, 256, 0, stream>>>(embed + 256, sums + 2048);
    k_bnfinal<<<1, 128, 0, stream>>>(sums + 2048, g3, be3);
    // final linear + softmax; BN3 affine fused on x3 columns (writes normalized x3)
    k_final<<<gF, 256, 0, stream>>>(embed, embed, sums + 2048 + 256, linW, linb, logits, probs);
}